// Round 5
// baseline (204.088 us; speedup 1.0000x reference)
//
#include <hip/hip_runtime.h>

#define M_ROWS 8192   // B*L
#define DIM    768    // D
#define HCH    128    // H
#define KSTEPS 24     // 768 / 32
#define NBLK   512    // grid size; 2 blocks/CU on 256 CUs -> all co-resident

typedef __bf16 bf16x8 __attribute__((ext_vector_type(8)));
typedef float  f32x4  __attribute__((ext_vector_type(4)));

// Poison-tolerant grid barrier: ctr starts at 0xAAAAAAAA (harness poison) or 0;
// every block CASes poison->0 before its first arrival, so the first atomic op
// on the cell in the total order is always a CAS. One counter, rising targets.
__device__ __forceinline__ void grid_arrive_wait(unsigned int* ctr, unsigned int target) {
    __syncthreads();                       // all lanes done with prior phase
    if (threadIdx.x == 0) {
        __threadfence();                   // release our phase's global writes
        __hip_atomic_fetch_add(ctr, 1u, __ATOMIC_ACQ_REL, __HIP_MEMORY_SCOPE_AGENT);
        long long guard = 0;
        while (__hip_atomic_load(ctr, __ATOMIC_ACQUIRE, __HIP_MEMORY_SCOPE_AGENT) < target) {
            if (++guard > (1LL << 30)) break;   // safety valve: never hang forever
            __builtin_amdgcn_s_sleep(2);
        }
    }
    __syncthreads();                       // fan acquire out to all lanes
}

// All-in-one: phase 1 converts W0 -> bf16 MFMA B-fragment layout (blocks 0-47),
// phase 2 is the barrier-free-K-loop MFMA GEMM + relu + weighted H-reduction
// (s1/s2), phase 3 is the outer sigmoid (each block: 16 rows x 1024 cols, s2
// staged in LDS). Grid barriers between phases replace 2 kernel-launch gaps.
__global__ __launch_bounds__(256) void fused_all_kernel(
    const float* __restrict__ text,
    const float* __restrict__ W0,
    const float* __restrict__ b0,
    const float* __restrict__ W1,
    const float* __restrict__ b1,
    bf16x8* __restrict__ W0f,
    float* __restrict__ s1, float* __restrict__ s2,
    unsigned int* __restrict__ ctr,
    float* __restrict__ out)
{
    __shared__ float red1[16][4];
    __shared__ float red2[16][4];
    __shared__ float s2s[1024];

    const int tid  = threadIdx.x;
    const int lane = tid & 63;
    const int wave = tid >> 6;
    const int n16  = lane & 15;
    const int quad = lane >> 4;
    const int row0 = blockIdx.x * 16;

    // normalize the poisoned counter exactly once, before any arrival
    if (tid == 0) atomicCAS(ctr, 0xAAAAAAAAu, 0u);

    // ---- phase 1: W0 f32 [128][768] -> B-frag-major bf16 ----
    // W0f[(c*KSTEPS + s)*64 + lane] = W0[c*16 + (lane&15)][s*32 + (lane>>4)*8 + j]
    {
        const int g = blockIdx.x * 256 + tid;       // 8*24*64 = 12288 items
        if (g < 8 * KSTEPS * 64) {
            const int c  = g / (KSTEPS * 64);
            const int r  = g - c * (KSTEPS * 64);
            const int s  = r >> 6;
            const int l  = r & 63;
            const float* src = W0 + (size_t)(c * 16 + (l & 15)) * DIM + s * 32 + (l >> 4) * 8;
            float4 v0 = *(const float4*)src;
            float4 v1 = *(const float4*)(src + 4);
            bf16x8 o;
            o[0] = (__bf16)v0.x; o[1] = (__bf16)v0.y; o[2] = (__bf16)v0.z; o[3] = (__bf16)v0.w;
            o[4] = (__bf16)v1.x; o[5] = (__bf16)v1.y; o[6] = (__bf16)v1.z; o[7] = (__bf16)v1.w;
            W0f[g] = o;
        }
    }
    grid_arrive_wait(ctr, NBLK);

    // ---- phase 2: barrier-free K-loop GEMM (M=8192,N=128,K=768) ----
    // Block = 4 waves over the SAME 16 rows (shared A lines -> L1 reuse);
    // wave w owns cols [w*32, w*32+32). Depth-2 register pipeline, no
    // __syncthreads in the K-loop -> no vmcnt(0) drains.
    {
        const int c0 = wave * 2;
        const float*  aptr  = text + (size_t)(row0 + n16) * DIM + quad * 8;
        const bf16x8* bptr0 = W0f + (size_t)(c0    ) * KSTEPS * 64 + lane;
        const bf16x8* bptr1 = W0f + (size_t)(c0 + 1) * KSTEPS * 64 + lane;

        f32x4 acc0 = (f32x4){0.f, 0.f, 0.f, 0.f};
        f32x4 acc1 = (f32x4){0.f, 0.f, 0.f, 0.f};

        float4 a0[3], a1[3];
        bf16x8 bv0[3], bv1[3];
        #pragma unroll
        for (int s = 0; s < 2; ++s) {
            a0[s]  = *(const float4*)(aptr + s * 32);
            a1[s]  = *(const float4*)(aptr + s * 32 + 4);
            bv0[s] = bptr0[s * 64];
            bv1[s] = bptr1[s * 64];
        }

        #pragma unroll
        for (int s = 0; s < KSTEPS; ++s) {
            const int sl = s % 3;
            const int pl = (s + 2) % 3;
            const int sp = (s + 2 < KSTEPS) ? (s + 2) : (s + 2 - KSTEPS);
            a0[pl]  = *(const float4*)(aptr + sp * 32);
            a1[pl]  = *(const float4*)(aptr + sp * 32 + 4);
            bv0[pl] = bptr0[sp * 64];
            bv1[pl] = bptr1[sp * 64];

            bf16x8 af;
            af[0] = (__bf16)a0[sl].x; af[1] = (__bf16)a0[sl].y;
            af[2] = (__bf16)a0[sl].z; af[3] = (__bf16)a0[sl].w;
            af[4] = (__bf16)a1[sl].x; af[5] = (__bf16)a1[sl].y;
            af[6] = (__bf16)a1[sl].z; af[7] = (__bf16)a1[sl].w;
            acc0 = __builtin_amdgcn_mfma_f32_16x16x32_bf16(af, bv0[sl], acc0, 0, 0, 0);
            acc1 = __builtin_amdgcn_mfma_f32_16x16x32_bf16(af, bv1[sl], acc1, 0, 0, 0);
        }

        // epilogue: relu + b0, weight by w_a/w_b, reduce this wave's 32 cols.
        // C/D layout (verified): col = lane&15 (+tile*16), row = quad*4 + reg
        float p1[4] = {0.f, 0.f, 0.f, 0.f};
        float p2[4] = {0.f, 0.f, 0.f, 0.f};
        #pragma unroll
        for (int j = 0; j < 2; ++j) {
            const f32x4 aj = j ? acc1 : acc0;
            const int col = wave * 32 + j * 16 + n16;
            const float bb = b0[col];
            const float wa = W1[col];
            const float wb = W1[HCH + col];
            #pragma unroll
            for (int r = 0; r < 4; ++r) {
                float h = aj[r] + bb;
                h = fmaxf(h, 0.f);
                p1[r] += h * wa;
                p2[r] += h * wb;
            }
        }
        #pragma unroll
        for (int r = 0; r < 4; ++r) {
            #pragma unroll
            for (int m = 8; m >= 1; m >>= 1) {   // stays inside each 16-lane group
                p1[r] += __shfl_xor(p1[r], m);
                p2[r] += __shfl_xor(p2[r], m);
            }
        }
        if (n16 == 0) {
            #pragma unroll
            for (int r = 0; r < 4; ++r) {
                const int rr = quad * 4 + r;
                red1[rr][wave] = p1[r];
                red2[rr][wave] = p2[r];
            }
        }
        __syncthreads();
        if (tid < 16) {
            s1[row0 + tid] = red1[tid][0] + red1[tid][1] + red1[tid][2] + red1[tid][3];
            s2[row0 + tid] = red2[tid][0] + red2[tid][1] + red2[tid][2] + red2[tid][3];
        }
    }
    grid_arrive_wait(ctr, 2 * NBLK);

    // ---- phase 3: out[b][i][j] = sigmoid(s1[b,i] + s2[b,j] + b1) ----
    // This block: rows [row0, row0+16), all in batch b = row0>>10.
    // Stage s2[b,:] (4 KB) in LDS once, then 16 coalesced float4 row-writes.
    {
        const int b = row0 >> 10;
        ((float4*)s2s)[tid] = ((const float4*)(s2 + (b << 10)))[tid];
        const float bias = b1[0];
        __syncthreads();
        const float4 t = ((const float4*)s2s)[tid];
        #pragma unroll 4
        for (int r = 0; r < 16; ++r) {
            const float base = s1[row0 + r] + bias;
            float4 o;
            o.x = 1.f / (1.f + __expf(-(base + t.x)));
            o.y = 1.f / (1.f + __expf(-(base + t.y)));
            o.z = 1.f / (1.f + __expf(-(base + t.z)));
            o.w = 1.f / (1.f + __expf(-(base + t.w)));
            ((float4*)out)[(size_t)(row0 + r) * 256 + tid] = o;
        }
    }
}

extern "C" void kernel_launch(void* const* d_in, const int* in_sizes, int n_in,
                              void* d_out, int out_size, void* d_ws, size_t ws_size,
                              hipStream_t stream)
{
    const float* text = (const float*)d_in[0];
    // d_in[1] = mask: all-ones, unused by the reference math
    const float* W0 = (const float*)d_in[2];
    const float* b0 = (const float*)d_in[3];
    const float* W1 = (const float*)d_in[4];
    const float* b1 = (const float*)d_in[5];
    float* out = (float*)d_out;

    // ws layout: [W0f frags: 192 KB][s1: 32 KB][s2: 32 KB][ctr: 4 B]
    bf16x8*       W0f = (bf16x8*)d_ws;
    float*        s1  = (float*)((char*)d_ws + 192 * 1024);
    float*        s2  = s1 + M_ROWS;
    unsigned int* ctr = (unsigned int*)((char*)d_ws + 256 * 1024);

    fused_all_kernel<<<NBLK, 256, 0, stream>>>(text, W0, b0, W1, b1,
                                               W0f, s1, s2, ctr, out);
}

// Round 6
// 103.005 us; speedup vs baseline: 1.9813x; 1.9813x over previous
//
#include <hip/hip_runtime.h>

#define M_ROWS 8192   // B*L
#define DIM    768    // D
#define HCH    128    // H
#define KSTEPS 24     // 768 / 32

typedef __bf16 bf16x8 __attribute__((ext_vector_type(8)));
typedef float  f32x4  __attribute__((ext_vector_type(4)));

// W0 f32 [128][768] -> bf16 in MFMA B-fragment-major layout:
//   W0f[(colTile*KSTEPS + kStep)*64 + lane] =
//   W0[colTile*16 + (lane&15)][kStep*32 + (lane>>4)*8 + j], j=0..7
// so the gemm's B-frag load is ONE coalesced dwordx4 per tile per k-step.
__global__ __launch_bounds__(256) void convert_w0_frag(
    const float* __restrict__ W0, bf16x8* __restrict__ W0f)
{
    const int g    = blockIdx.x * 256 + threadIdx.x;   // 8*24*64 = 12288 total
    const int c    = g / (KSTEPS * 64);
    const int r    = g - c * (KSTEPS * 64);
    const int s    = r >> 6;
    const int lane = r & 63;
    const float* src = W0 + (size_t)(c * 16 + (lane & 15)) * DIM + s * 32 + (lane >> 4) * 8;
    float4 v0 = *(const float4*)src;
    float4 v1 = *(const float4*)(src + 4);
    bf16x8 o;
    o[0] = (__bf16)v0.x; o[1] = (__bf16)v0.y; o[2] = (__bf16)v0.z; o[3] = (__bf16)v0.w;
    o[4] = (__bf16)v1.x; o[5] = (__bf16)v1.y; o[6] = (__bf16)v1.z; o[7] = (__bf16)v1.w;
    W0f[g] = o;
}

// Barrier-free, LDS-free fused GEMM (M=8192,N=128,K=768 bf16 MFMA) + relu +
// weighted H-reduction. Block = 4 waves over the SAME 16 rows (shared A lines
// hit L1); wave w owns cols [w*32, w*32+32). Grid 512 -> 2 blocks/CU.
// K-loop: NAMED ping-pong prefetch (no arrays, no % rotation) so the
// pipeline lives in registers — round 5's array version was demoted to
// scratch (VGPR_Count 52 < 66 needed) and ran 129 us on scratch latency.
__global__ __launch_bounds__(256) void gemm_s_kernel(
    const float* __restrict__ text,
    const bf16x8* __restrict__ W0f,
    const float* __restrict__ b0,
    const float* __restrict__ W1,
    float* __restrict__ s1, float* __restrict__ s2)
{
    __shared__ float red1[16][4];
    __shared__ float red2[16][4];

    const int tid  = threadIdx.x;
    const int lane = tid & 63;
    const int wave = tid >> 6;
    const int n16  = lane & 15;
    const int quad = lane >> 4;
    const int row0 = blockIdx.x * 16;
    const int c0   = wave * 2;           // this wave's two 16-col tiles

    // A: lane holds A[row=n16][k = s*32 + quad*8 .. +7] (f32, cvt on use).
    const float*  aptr  = text + (size_t)(row0 + n16) * DIM + quad * 8;
    const bf16x8* bptr0 = W0f + (size_t)(c0    ) * KSTEPS * 64 + lane;
    const bf16x8* bptr1 = W0f + (size_t)(c0 + 1) * KSTEPS * 64 + lane;

    f32x4 acc0 = (f32x4){0.f, 0.f, 0.f, 0.f};
    f32x4 acc1 = (f32x4){0.f, 0.f, 0.f, 0.f};

    // current buffers (named, SSA-friendly)
    float4 a0c = *(const float4*)(aptr);
    float4 a1c = *(const float4*)(aptr + 4);
    bf16x8 b0c = bptr0[0];
    bf16x8 b1c = bptr1[0];

    #pragma unroll
    for (int s = 0; s < KSTEPS; ++s) {
        const int sp = (s + 1 < KSTEPS) ? (s + 1) : 0;   // harmless wrap on last
        float4 a0n = *(const float4*)(aptr + sp * 32);
        float4 a1n = *(const float4*)(aptr + sp * 32 + 4);
        bf16x8 b0n = bptr0[sp * 64];
        bf16x8 b1n = bptr1[sp * 64];

        bf16x8 af;
        af[0] = (__bf16)a0c.x; af[1] = (__bf16)a0c.y;
        af[2] = (__bf16)a0c.z; af[3] = (__bf16)a0c.w;
        af[4] = (__bf16)a1c.x; af[5] = (__bf16)a1c.y;
        af[6] = (__bf16)a1c.z; af[7] = (__bf16)a1c.w;
        acc0 = __builtin_amdgcn_mfma_f32_16x16x32_bf16(af, b0c, acc0, 0, 0, 0);
        acc1 = __builtin_amdgcn_mfma_f32_16x16x32_bf16(af, b1c, acc1, 0, 0, 0);

        a0c = a0n; a1c = a1n; b0c = b0n; b1c = b1n;
    }

    // epilogue: relu + b0, weight by w_a / w_b, reduce this wave's 32 cols.
    // C/D layout (verified): col = lane&15 (+tile*16), row = quad*4 + reg
    float p1[4] = {0.f, 0.f, 0.f, 0.f};
    float p2[4] = {0.f, 0.f, 0.f, 0.f};
    #pragma unroll
    for (int j = 0; j < 2; ++j) {
        const f32x4 aj = j ? acc1 : acc0;
        const int col = wave * 32 + j * 16 + n16;
        const float bb = b0[col];
        const float wa = W1[col];
        const float wb = W1[HCH + col];
        #pragma unroll
        for (int r = 0; r < 4; ++r) {
            float h = aj[r] + bb;
            h = fmaxf(h, 0.f);
            p1[r] += h * wa;
            p2[r] += h * wb;
        }
    }
    // reduce across the 16 lanes of each quad (masks < 16 stay in the group)
    #pragma unroll
    for (int r = 0; r < 4; ++r) {
        #pragma unroll
        for (int m = 8; m >= 1; m >>= 1) {
            p1[r] += __shfl_xor(p1[r], m);
            p2[r] += __shfl_xor(p2[r], m);
        }
    }
    if (n16 == 0) {
        #pragma unroll
        for (int r = 0; r < 4; ++r) {
            const int rr = quad * 4 + r;
            red1[rr][wave] = p1[r];
            red2[rr][wave] = p2[r];
        }
    }
    __syncthreads();
    if (tid < 16) {
        s1[row0 + tid] = red1[tid][0] + red1[tid][1] + red1[tid][2] + red1[tid][3];
        s2[row0 + tid] = red2[tid][0] + red2[tid][1] + red2[tid][2] + red2[tid][3];
    }
}

// out[b][i][j] = sigmoid(s1[b*1024+i] + s2[b*1024+j] + b1)
// grid = 8192 (one block per (b,i) row), 256 thr x float4 = 1024 j's
__global__ __launch_bounds__(256) void outer_sigmoid_kernel(
    const float* __restrict__ s1, const float* __restrict__ s2,
    const float* __restrict__ b1, float* __restrict__ out)
{
    const int bi = blockIdx.x;
    const int b  = bi >> 10;
    const float base = s1[bi] + b1[0];
    const float4 t = ((const float4*)(s2 + (b << 10)))[threadIdx.x];
    float4 r;
    r.x = 1.f / (1.f + __expf(-(base + t.x)));
    r.y = 1.f / (1.f + __expf(-(base + t.y)));
    r.z = 1.f / (1.f + __expf(-(base + t.z)));
    r.w = 1.f / (1.f + __expf(-(base + t.w)));
    ((float4*)out)[((size_t)bi << 8) + threadIdx.x] = r;
}

extern "C" void kernel_launch(void* const* d_in, const int* in_sizes, int n_in,
                              void* d_out, int out_size, void* d_ws, size_t ws_size,
                              hipStream_t stream)
{
    const float* text = (const float*)d_in[0];
    // d_in[1] = mask: all-ones, unused by the reference math
    const float* W0 = (const float*)d_in[2];
    const float* b0 = (const float*)d_in[3];
    const float* W1 = (const float*)d_in[4];
    const float* b1 = (const float*)d_in[5];
    float* out = (float*)d_out;

    // ws layout: [W0f bf16 frags: 192 KB][s1: 32 KB][s2: 32 KB]
    bf16x8* W0f = (bf16x8*)d_ws;
    float* s1 = (float*)((char*)d_ws + 192 * 1024);
    float* s2 = s1 + M_ROWS;

    convert_w0_frag<<<48, 256, 0, stream>>>(W0, W0f);
    gemm_s_kernel<<<512, 256, 0, stream>>>(text, W0f, b0, W1, s1, s2);
    outer_sigmoid_kernel<<<8192, 256, 0, stream>>>(s1, s2, b1, out);
}